// Round 7
// baseline (15677.673 us; speedup 1.0000x reference)
//
#include <hip/hip_runtime.h>

#define B_   64
#define T_   512
#define KIN  512
#define NH   512
#define KEFF 3072   // 6 segments x 512
#define NBLK 64
#define NTHR 512

typedef __attribute__((ext_vector_type(8))) short short8;
typedef __attribute__((ext_vector_type(4))) float f32x4;
typedef __attribute__((ext_vector_type(4))) unsigned int u32x4;

// bf16 round-to-nearest-even via bit ops
__device__ __forceinline__ unsigned short f2b(float f) {
    union { float f; unsigned int u; } v; v.f = f;
    unsigned int u = v.u;
    return (unsigned short)((u + 0x7FFFu + ((u >> 16) & 1u)) >> 16);
}
__device__ __forceinline__ float b2f(unsigned short h) {
    union { float f; unsigned int u; } v; v.u = ((unsigned int)h) << 16;
    return v.f;
}

// ---------------------------------------------------------------------------
// Prepack (proven): B' [n][keff] bf16. Segments:
//   seg0: Whi(H) seg1: Whi(H) seg2: Wlo(H) seg3: Whi(X) seg4: Whi(X) seg5: Wlo(X)
// ---------------------------------------------------------------------------
__global__ void prepack(const float* __restrict__ Wxz, const float* __restrict__ Whz,
                        const float* __restrict__ Wxr, const float* __restrict__ Whr,
                        const float* __restrict__ Wxh, const float* __restrict__ Whh,
                        unsigned short* __restrict__ Bzr, unsigned short* __restrict__ Bh) {
    int keff = blockIdx.x * 256 + threadIdx.x;  // 0..3071
    int n    = blockIdx.y;                      // 0..1535
    int seg  = keff >> 9;
    int k    = keff & 511;
    const float* src;
    int c;
    if (n < 512)       { c = n;        src = (seg < 3) ? Whz : Wxz; }
    else if (n < 1024) { c = n - 512;  src = (seg < 3) ? Whr : Wxr; }
    else               { c = n - 1024; src = (seg < 3) ? Whh : Wxh; }
    float w = src[k * NH + c];
    unsigned short hi = f2b(w);
    unsigned short o  = (seg == 2 || seg == 5) ? f2b(w - b2f(hi)) : hi;
    if (n < 1024) Bzr[(size_t)n * KEFF + keff] = o;
    else          Bh[(size_t)(n - 1024) * KEFF + keff] = o;
}

// Coherent ops (proven): relaxed+agent -> sc-bit loads/stores, no cache
// maintenance anywhere -> weights stay L2-warm all 512 steps.
__device__ __forceinline__ unsigned int ald32(const unsigned int* p) {
    return __hip_atomic_load(p, __ATOMIC_RELAXED, __HIP_MEMORY_SCOPE_AGENT);
}
__device__ __forceinline__ unsigned long long ald64(const void* p) {
    return __hip_atomic_load((const unsigned long long*)p, __ATOMIC_RELAXED,
                             __HIP_MEMORY_SCOPE_AGENT);
}
__device__ __forceinline__ void ast32(unsigned int* p, unsigned int v) {
    __hip_atomic_store(p, v, __ATOMIC_RELAXED, __HIP_MEMORY_SCOPE_AGENT);
}
__device__ __forceinline__ void ast64(void* p, unsigned long long v) {
    __hip_atomic_store((unsigned long long*)p, v, __ATOMIC_RELAXED,
                       __HIP_MEMORY_SCOPE_AGENT);
}

// Flag barrier: arrival = store own slot; wait = wave-0 64-lane coalesced
// poll + __all vote, with s_sleep backoff (cuts MALL poll pressure that
// queues ahead of stragglers' store-acks).
__device__ __forceinline__ void flag_wait(const unsigned int* flags,
                                          unsigned int tgt, int lane) {
    while (1) {
        unsigned int v = ald32(flags + lane);
        if (__all((int)(v >= tgt))) break;
        __builtin_amdgcn_s_sleep(2);
    }
    __builtin_amdgcn_sched_barrier(0);
}

// XOR-permuted global word index for HP/RHP (matches linear staging order +
// swizzled ds_read).
__device__ __forceinline__ int hp_idx(int m, int c) {
    return m * 512 + (c ^ ((m & 7) << 2));
}

// fp32 -> bf16 hi/lo split of 8 consecutive X elements
__device__ __forceinline__ void cvt_x8(const float* xr, int kp, short8* ahi, short8* alo) {
    f32x4 x0 = *(const f32x4*)(xr + kp);
    f32x4 x1 = *(const f32x4*)(xr + kp + 4);
#pragma unroll
    for (int i = 0; i < 4; ++i) {
        unsigned short h0 = f2b(x0[i]);
        (*ahi)[i] = (short)h0; (*alo)[i] = (short)f2b(x0[i] - b2f(h0));
        unsigned short h1 = f2b(x1[i]);
        (*ahi)[4 + i] = (short)h1; (*alo)[4 + i] = (short)f2b(x1[i] - b2f(h1));
    }
}

// 8 packed u32 (hi|lo<<16) -> hi/lo short8 fragments
__device__ __forceinline__ void unpackw(u32x4 w0, u32x4 w1, short8* ahi, short8* alo) {
    union { unsigned int u[4]; short8 v; } H, L;
    H.u[0] = __builtin_amdgcn_perm(w0[1], w0[0], 0x05040100u);
    H.u[1] = __builtin_amdgcn_perm(w0[3], w0[2], 0x05040100u);
    H.u[2] = __builtin_amdgcn_perm(w1[1], w1[0], 0x05040100u);
    H.u[3] = __builtin_amdgcn_perm(w1[3], w1[2], 0x05040100u);
    L.u[0] = __builtin_amdgcn_perm(w0[1], w0[0], 0x07060302u);
    L.u[1] = __builtin_amdgcn_perm(w0[3], w0[2], 0x07060302u);
    L.u[2] = __builtin_amdgcn_perm(w1[1], w1[0], 0x07060302u);
    L.u[3] = __builtin_amdgcn_perm(w1[3], w1[2], 0x07060302u);
    *ahi = H.v; *alo = L.v;
}

#define MFMA(a, b, c) __builtin_amdgcn_mfma_f32_16x16x32_bf16((a), (b), (c), 0, 0, 0)

// ---------------------------------------------------------------------------
// Persistent GRU, wave-specialized (round-6 structure). ONE change: coherent
// staging now uses pipelined register loads (__hip_atomic_load u64 pairs,
// 16 loads/batch, 2-deep pipeline, vmcnt-tracked) + ds_write_b128, instead
// of coherent global_load_lds (suspected serialized at the LDS-DMA unit).
// ---------------------------------------------------------------------------
__global__ void __launch_bounds__(NTHR, 2) gru_seq(
    const float* __restrict__ X, const float* __restrict__ bz,
    const float* __restrict__ br, const float* __restrict__ bh,
    float* __restrict__ out, float* __restrict__ Zt,
    unsigned int* __restrict__ HP, unsigned int* __restrict__ RHP,
    const unsigned short* __restrict__ Bzr, const unsigned short* __restrict__ Bh,
    unsigned int* flags) {
    const int blk  = blockIdx.x;
    const int tid  = threadIdx.x;
    const int wv   = tid >> 6;          // 0..7
    const int hwv  = wv & 3;            // role-local wave id
    const bool xcrew = wv >= 4;
    const int lane = tid & 63;
    const int fm   = lane & 15;
    const int fkc  = lane >> 4;
    const int fk   = fkc * 8;

    __shared__ unsigned int hbuf[4 * 16 * 512];   // 128 KB H/RH staging
    __shared__ float xp1[2][4][16][16];           // 8 KB  P1 X-preacts (dbuf)
    __shared__ float xp2a[2][2][16][16];          // 4 KB  P2 X-preacts jh=0
    __shared__ float xp2b[2][2][16][16];          // 4 KB  P2 X-preacts jh=1
    __shared__ float comb[2][256];                // 2 KB  P2 H-part K-combine

    // phase-1 geometry: block owns zr-ntile blk, wave hwv owns mtile hwv
    const int m1 = hwv * 16 + fm;
    const unsigned short* Bp1 = Bzr + (size_t)(blk * 16 + fm) * KEFF;
    const int c1 = blk * 16 + fm;

    // phase-2 geometry: mt = blk&3; tasks s2i in {0,1} -> nt; jh = K-half
    const int mt  = blk & 3;
    const int s2i = hwv >> 1;
    const int jh  = hwv & 1;
    const int nt  = (blk >> 2) * 2 + s2i;
    const int m2  = mt * 16 + fm;
    const unsigned short* Bp2 = Bh + (size_t)(nt * 16 + fm) * KEFF;
    const int c2 = nt * 16 + fm;

    const int key = (fm & 7) << 4;
    const int sw0 = (32 * fkc) ^ key;
    const int sw1 = (32 * fkc + 16) ^ key;
    const char* HPb  = (const char*)HP;
    const char* RHPb = (const char*)RHP;

    const float bias1 = (blk < 32) ? bz[c1] : br[c1 - 512];
    const float bhi   = bh[c2];

    const int l2 = lane * 2;

    // X-crew producers ------------------------------------------------------
    auto xg1 = [&](int tt, int buf) {   // P1 X-preacts: mtile hwv, 16 zr-cols
        f32x4 acc = {0.f, 0.f, 0.f, 0.f};
        const float* xr = X + (size_t)m1 * (T_ * KIN) + (size_t)tt * KIN;
#pragma unroll 4
        for (int j = 0; j < 16; ++j) {
            int kp = j * 32 + fk;
            short8 xhi, xlo; cvt_x8(xr, kp, &xhi, &xlo);
            short8 b3 = *(const short8*)(Bp1 + 1536 + kp);
            short8 b4 = *(const short8*)(Bp1 + 2048 + kp);
            short8 b5 = *(const short8*)(Bp1 + 2560 + kp);
            acc = MFMA(xhi, b3, acc); acc = MFMA(xlo, b4, acc); acc = MFMA(xhi, b5, acc);
        }
#pragma unroll
        for (int jj = 0; jj < 4; ++jj) xp1[buf][hwv][fkc * 4 + jj][fm] = acc[jj];
    };
    auto xg2 = [&](int tt, int buf) {   // P2 X-preacts: (mt, nt(s2i)), K-half jh
        f32x4 acc = {0.f, 0.f, 0.f, 0.f};
        const float* xr = X + (size_t)m2 * (T_ * KIN) + (size_t)tt * KIN;
#pragma unroll
        for (int j = jh * 8; j < jh * 8 + 8; ++j) {
            int kp = j * 32 + fk;
            short8 xhi, xlo; cvt_x8(xr, kp, &xhi, &xlo);
            short8 b3 = *(const short8*)(Bp2 + 1536 + kp);
            short8 b4 = *(const short8*)(Bp2 + 2048 + kp);
            short8 b5 = *(const short8*)(Bp2 + 2560 + kp);
            acc = MFMA(xhi, b3, acc); acc = MFMA(xlo, b4, acc); acc = MFMA(xhi, b5, acc);
        }
        float (*dst)[16][16] = jh ? xp2b[buf] : xp2a[buf];
#pragma unroll
        for (int jj = 0; jj < 4; ++jj) dst[s2i][fkc * 4 + jj][fm] = acc[jj];
    };

    // prologue: X-preacts for t=0
    if (xcrew) { xg1(0, 0); xg2(0, 0); }
    __syncthreads();                                   // S0

    for (int t = 0; t < T_; ++t) {
        const int bufc = t & 1, bufn = bufc ^ 1;
        const unsigned int ep = (unsigned int)t * 2u;
        // ------------------------- phase 1: Z and R -------------------------
        if (wv == 0 && t) flag_wait(flags, ep, lane);  // H(t-1) published
        __syncthreads();                               // S1
        if (!xcrew) {
            // stage own 32 KB H slice -> LDS via pipelined coherent reg loads
            // (4 batches of 8 rounds x 16B/lane; 2 batches in flight)
            {
                const unsigned long long* sq =
                    (const unsigned long long*)(HPb + hwv * 32768);
                char* dstc = (char*)hbuf + hwv * 32768;
                unsigned long long a0[16], a1[16];
#pragma unroll
                for (int i = 0; i < 8; ++i) {          // issue batch 0
                    a0[2*i]   = ald64(sq + i * 128 + l2);
                    a0[2*i+1] = ald64(sq + i * 128 + l2 + 1);
                }
#pragma unroll
                for (int i = 0; i < 8; ++i) {          // issue batch 1
                    a1[2*i]   = ald64(sq + (i + 8) * 128 + l2);
                    a1[2*i+1] = ald64(sq + (i + 8) * 128 + l2 + 1);
                }
#pragma unroll
                for (int i = 0; i < 8; ++i) {          // write 0
                    union { unsigned long long q[2]; u32x4 v; } tq;
                    tq.q[0] = a0[2*i]; tq.q[1] = a0[2*i+1];
                    *(u32x4*)(dstc + i * 1024 + lane * 16) = tq.v;
                }
#pragma unroll
                for (int i = 0; i < 8; ++i) {          // issue batch 2
                    a0[2*i]   = ald64(sq + (i + 16) * 128 + l2);
                    a0[2*i+1] = ald64(sq + (i + 16) * 128 + l2 + 1);
                }
#pragma unroll
                for (int i = 0; i < 8; ++i) {          // write 1
                    union { unsigned long long q[2]; u32x4 v; } tq;
                    tq.q[0] = a1[2*i]; tq.q[1] = a1[2*i+1];
                    *(u32x4*)(dstc + (i + 8) * 1024 + lane * 16) = tq.v;
                }
#pragma unroll
                for (int i = 0; i < 8; ++i) {          // issue batch 3
                    a1[2*i]   = ald64(sq + (i + 24) * 128 + l2);
                    a1[2*i+1] = ald64(sq + (i + 24) * 128 + l2 + 1);
                }
#pragma unroll
                for (int i = 0; i < 8; ++i) {          // write 2
                    union { unsigned long long q[2]; u32x4 v; } tq;
                    tq.q[0] = a0[2*i]; tq.q[1] = a0[2*i+1];
                    *(u32x4*)(dstc + (i + 16) * 1024 + lane * 16) = tq.v;
                }
#pragma unroll
                for (int i = 0; i < 8; ++i) {          // write 3
                    union { unsigned long long q[2]; u32x4 v; } tq;
                    tq.q[0] = a1[2*i]; tq.q[1] = a1[2*i+1];
                    *(u32x4*)(dstc + (i + 24) * 1024 + lane * 16) = tq.v;
                }
            }
            // H-GEMM (segs 0..2) from LDS (same-wave ds deps compiler-tracked)
            f32x4 acc = {0.f, 0.f, 0.f, 0.f};
            const char* sl = (const char*)hbuf + hwv * 32768 + fm * 2048;
#pragma unroll 4
            for (int j = 0; j < 16; ++j) {
                u32x4 w0 = *(const u32x4*)(sl + 128 * j + sw0);
                u32x4 w1 = *(const u32x4*)(sl + 128 * j + sw1);
                short8 ahi, alo; unpackw(w0, w1, &ahi, &alo);
                int kp = j * 32 + fk;
                short8 b0 = *(const short8*)(Bp1 + kp);
                short8 b1 = *(const short8*)(Bp1 + 512 + kp);
                short8 b2 = *(const short8*)(Bp1 + 1024 + kp);
                acc = MFMA(ahi, b0, acc); acc = MFMA(alo, b1, acc); acc = MFMA(ahi, b2, acc);
            }
            if (blk < 32) {             // z-gate -> Zt [c][m]
                float g[4];
#pragma unroll
                for (int jj = 0; jj < 4; ++jj)
                    g[jj] = 1.f / (1.f + __expf(-(acc[jj] +
                              xp1[bufc][hwv][fkc * 4 + jj][fm] + bias1)));
                union { float f[2]; unsigned long long q; } p0, p1;
                p0.f[0] = g[0]; p0.f[1] = g[1];
                p1.f[0] = g[2]; p1.f[1] = g[3];
                float* zp = Zt + c1 * 64 + hwv * 16 + fkc * 4;
                ast64(zp, p0.q); ast64(zp + 2, p1.q);
            } else {                    // r-gate -> RH packed (H from LDS)
                int cr = c1 - 512;
#pragma unroll
                for (int jj = 0; jj < 4; ++jj) {
                    int lr = fkc * 4 + jj;
                    unsigned int hw = *(const unsigned int*)((const char*)hbuf +
                        hwv * 32768 + lr * 2048 + ((4 * cr) ^ ((lr & 7) << 4)));
                    float h  = b2f((unsigned short)(hw & 0xffffu)) +
                               b2f((unsigned short)(hw >> 16));
                    float gr = 1.f / (1.f + __expf(-(acc[jj] +
                                 xp1[bufc][hwv][lr][fm] + bias1)));
                    float rh = gr * h;
                    unsigned short hi = f2b(rh);
                    unsigned short lo = f2b(rh - b2f(hi));
                    ast32(RHP + hp_idx(hwv * 16 + lr, cr),
                          (unsigned int)hi | ((unsigned int)lo << 16));
                }
            }
        } else if (t + 1 < T_) {
            xg1(t + 1, bufn);           // off-path: next step's P1 X-preacts
        }
        __syncthreads();                               // S2: drains stores
        if (tid == 0) ast32(flags + blk, ep + 1u);     // B1 arrive
        // ------------------------- phase 2: h~ and H update ------------------
        if (wv == 0) flag_wait(flags, ep + 1u, lane);  // all P1 done
        if (xcrew && t + 1 < T_) xg2(t + 1, bufn);     // overlaps the poll
        __syncthreads();                               // S3
        unsigned long long zq0 = 0, zq1 = 0;
        if (!xcrew) {
            if (jh == 0) {              // prefetch Z (hides MALL latency)
                const float* zp = Zt + c2 * 64 + mt * 16 + fkc * 4;
                zq0 = ald64(zp); zq1 = ald64(zp + 2);
            }
            // stage RH rows [16mt,16mt+16) -> slice (mt+2)&3, reg-pipelined
            {
                const unsigned long long* sq =
                    (const unsigned long long*)(RHPb + mt * 32768);
                char* dstc = (char*)hbuf + ((mt + 2) & 3) * 32768;
                unsigned long long a[16];
#pragma unroll
                for (int i = 0; i < 8; ++i) {
                    int r = hwv * 8 + i;
                    a[2*i]   = ald64(sq + r * 128 + l2);
                    a[2*i+1] = ald64(sq + r * 128 + l2 + 1);
                }
#pragma unroll
                for (int i = 0; i < 8; ++i) {
                    int r = hwv * 8 + i;
                    union { unsigned long long q[2]; u32x4 v; } tq;
                    tq.q[0] = a[2*i]; tq.q[1] = a[2*i+1];
                    *(u32x4*)(dstc + r * 1024 + lane * 16) = tq.v;
                }
            }
        }
        __syncthreads();                               // S3b: staged RH visible
        f32x4 acc2 = {0.f, 0.f, 0.f, 0.f};
        if (!xcrew) {
            // RH-GEMM (segs 0..2), K-half jh
            const char* sl2 = (const char*)hbuf + ((mt + 2) & 3) * 32768 + fm * 2048;
#pragma unroll
            for (int j = jh * 8; j < jh * 8 + 8; ++j) {
                u32x4 w0 = *(const u32x4*)(sl2 + 128 * j + sw0);
                u32x4 w1 = *(const u32x4*)(sl2 + 128 * j + sw1);
                short8 ahi, alo; unpackw(w0, w1, &ahi, &alo);
                int kp = j * 32 + fk;
                short8 b0 = *(const short8*)(Bp2 + kp);
                short8 b1 = *(const short8*)(Bp2 + 512 + kp);
                short8 b2 = *(const short8*)(Bp2 + 1024 + kp);
                acc2 = MFMA(ahi, b0, acc2); acc2 = MFMA(alo, b1, acc2); acc2 = MFMA(ahi, b2, acc2);
            }
            if (jh == 1) {
#pragma unroll
                for (int jj = 0; jj < 4; ++jj)
                    comb[s2i][(fkc * 4 + jj) * 16 + fm] = acc2[jj];
            }
        }
        __syncthreads();                               // S4a: comb ready
        if (!xcrew && jh == 0) {
            union { unsigned long long q; float f[2]; } z0, z1;
            z0.q = zq0; z1.q = zq1;
            float zv[4] = {z0.f[0], z0.f[1], z1.f[0], z1.f[1]};
#pragma unroll
            for (int jj = 0; jj < 4; ++jj) {
                int lr   = fkc * 4 + jj;
                int mrow = mt * 16 + lr;
                unsigned int hw = *(const unsigned int*)((const char*)hbuf +
                    mt * 32768 + lr * 2048 + ((4 * c2) ^ ((lr & 7) << 4)));
                float h   = b2f((unsigned short)(hw & 0xffffu)) +
                            b2f((unsigned short)(hw >> 16));
                float pre = acc2[jj] + comb[s2i][lr * 16 + fm] +
                            xp2a[bufc][s2i][lr][fm] + xp2b[bufc][s2i][lr][fm] + bhi;
                float e   = __expf(-2.f * pre);
                float ht  = 2.f / (1.f + e) - 1.f;     // tanh
                float hn  = zv[jj] * h + (1.f - zv[jj]) * ht;
                out[(size_t)mrow * (T_ * NH) + (size_t)t * NH + c2] = hn;
                if (t == T_ - 1)
                    out[(size_t)B_ * T_ * NH + mrow * NH + c2] = hn;
                unsigned short hi = f2b(hn);
                unsigned short lo = f2b(hn - b2f(hi));
                ast32(HP + hp_idx(mrow, c2),
                      (unsigned int)hi | ((unsigned int)lo << 16));
            }
        }
        __syncthreads();                               // S4: drains stores
        if (tid == 0) ast32(flags + blk, ep + 2u);     // B2 arrive
    }
}

extern "C" void kernel_launch(void* const* d_in, const int* in_sizes, int n_in,
                              void* d_out, int out_size, void* d_ws, size_t ws_size,
                              hipStream_t stream) {
    (void)in_sizes; (void)n_in; (void)out_size; (void)ws_size;
    const float* X   = (const float*)d_in[0];
    const float* Wxz = (const float*)d_in[1];
    const float* Whz = (const float*)d_in[2];
    const float* bz  = (const float*)d_in[3];
    const float* Wxr = (const float*)d_in[4];
    const float* Whr = (const float*)d_in[5];
    const float* br  = (const float*)d_in[6];
    const float* Wxh = (const float*)d_in[7];
    const float* Whh = (const float*)d_in[8];
    const float* bh  = (const float*)d_in[9];
    float* out = (float*)d_out;

    char* ws = (char*)d_ws;
    unsigned int* flags = (unsigned int*)ws;                      // 256 B (64 slots)
    float* Zt         = (float*)(ws + 256);                       // 128 KB [c][m]
    unsigned int* HP  = (unsigned int*)(ws + 256 + 131072);       // 128 KB packed+swz
    unsigned int* RHP = (unsigned int*)(ws + 256 + 262144);       // 128 KB packed+swz
    unsigned short* Bzr = (unsigned short*)(ws + (1 << 20));      // 6.3 MB
    unsigned short* Bh  = Bzr + (size_t)1024 * KEFF;              // 3.2 MB

    // zero flags + H0 state each call (graph-replay safe)
    hipMemsetAsync(d_ws, 0, 1 << 20, stream);
    prepack<<<dim3(12, 1536), 256, 0, stream>>>(Wxz, Whz, Wxr, Whr, Wxh, Whh, Bzr, Bh);
    gru_seq<<<NBLK, NTHR, 0, stream>>>(X, bz, br, bh, out, Zt, HP, RHP, Bzr, Bh, flags);
}

// Round 8
// 13237.627 us; speedup vs baseline: 1.1843x; 1.1843x over previous
//
#include <hip/hip_runtime.h>

#define B_   64
#define T_   512
#define KIN  512
#define NH   512
#define KEFF 3072   // 6 segments x 512
#define NBLK 64
#define NTHR 512

typedef __attribute__((ext_vector_type(8))) short short8;
typedef __attribute__((ext_vector_type(4))) float f32x4;
typedef __attribute__((ext_vector_type(4))) unsigned int u32x4;

// bf16 round-to-nearest-even via bit ops
__device__ __forceinline__ unsigned short f2b(float f) {
    union { float f; unsigned int u; } v; v.f = f;
    unsigned int u = v.u;
    return (unsigned short)((u + 0x7FFFu + ((u >> 16) & 1u)) >> 16);
}
__device__ __forceinline__ float b2f(unsigned short h) {
    union { float f; unsigned int u; } v; v.u = ((unsigned int)h) << 16;
    return v.f;
}

// ---------------------------------------------------------------------------
// Prepack (proven, unchanged): B' [n][keff] bf16. Segments:
//   seg0: Whi(H) seg1: Whi(H) seg2: Wlo(H) seg3: Whi(X) seg4: Whi(X) seg5: Wlo(X)
// ---------------------------------------------------------------------------
__global__ void prepack(const float* __restrict__ Wxz, const float* __restrict__ Whz,
                        const float* __restrict__ Wxr, const float* __restrict__ Whr,
                        const float* __restrict__ Wxh, const float* __restrict__ Whh,
                        unsigned short* __restrict__ Bzr, unsigned short* __restrict__ Bh) {
    int keff = blockIdx.x * 256 + threadIdx.x;  // 0..3071
    int n    = blockIdx.y;                      // 0..1535
    int seg  = keff >> 9;
    int k    = keff & 511;
    const float* src;
    int c;
    if (n < 512)       { c = n;        src = (seg < 3) ? Whz : Wxz; }
    else if (n < 1024) { c = n - 512;  src = (seg < 3) ? Whr : Wxr; }
    else               { c = n - 1024; src = (seg < 3) ? Whh : Wxh; }
    float w = src[k * NH + c];
    unsigned short hi = f2b(w);
    unsigned short o  = (seg == 2 || seg == 5) ? f2b(w - b2f(hi)) : hi;
    if (n < 1024) Bzr[(size_t)n * KEFF + keff] = o;
    else          Bh[(size_t)(n - 1024) * KEFF + keff] = o;
}

// Coherent ops (proven): relaxed+agent -> sc-bit loads/stores, no cache
// maintenance anywhere -> weights stay L2-warm all 512 steps.
__device__ __forceinline__ unsigned int ald32(const unsigned int* p) {
    return __hip_atomic_load(p, __ATOMIC_RELAXED, __HIP_MEMORY_SCOPE_AGENT);
}
__device__ __forceinline__ unsigned long long ald64(const void* p) {
    return __hip_atomic_load((const unsigned long long*)p, __ATOMIC_RELAXED,
                             __HIP_MEMORY_SCOPE_AGENT);
}
__device__ __forceinline__ void ast32(unsigned int* p, unsigned int v) {
    __hip_atomic_store(p, v, __ATOMIC_RELAXED, __HIP_MEMORY_SCOPE_AGENT);
}
__device__ __forceinline__ void ast64(void* p, unsigned long long v) {
    __hip_atomic_store((unsigned long long*)p, v, __ATOMIC_RELAXED,
                       __HIP_MEMORY_SCOPE_AGENT);
}

// Group flag barrier: 16 participants. Arrival = store own slot; wait =
// wave-0 lanes 0..15 poll the group's 16 flags (one 64B line) + __all vote.
__device__ __forceinline__ void flag_wait16(const unsigned int* flg,
                                            unsigned int tgt, int fidx) {
    while (1) {
        unsigned int v = ald32(flg + fidx);
        if (__all((int)(v >= tgt))) break;
    }
    __builtin_amdgcn_sched_barrier(0);
}

// XOR-permuted word index for 16-row packed state buffers (matches linear
// gload_lds staging + swizzled ds_read).
__device__ __forceinline__ int hp_idx(int m, int c) {
    return m * 512 + (c ^ ((m & 7) << 2));
}

// fp32 -> bf16 hi/lo split of 8 consecutive X elements
__device__ __forceinline__ void cvt_x8(const float* xr, int kp, short8* ahi, short8* alo) {
    f32x4 x0 = *(const f32x4*)(xr + kp);
    f32x4 x1 = *(const f32x4*)(xr + kp + 4);
#pragma unroll
    for (int i = 0; i < 4; ++i) {
        unsigned short h0 = f2b(x0[i]);
        (*ahi)[i] = (short)h0; (*alo)[i] = (short)f2b(x0[i] - b2f(h0));
        unsigned short h1 = f2b(x1[i]);
        (*ahi)[4 + i] = (short)h1; (*alo)[4 + i] = (short)f2b(x1[i] - b2f(h1));
    }
}

// 8 packed u32 (hi|lo<<16) -> hi/lo short8 fragments
__device__ __forceinline__ void unpackw(u32x4 w0, u32x4 w1, short8* ahi, short8* alo) {
    union { unsigned int u[4]; short8 v; } H, L;
    H.u[0] = __builtin_amdgcn_perm(w0[1], w0[0], 0x05040100u);
    H.u[1] = __builtin_amdgcn_perm(w0[3], w0[2], 0x05040100u);
    H.u[2] = __builtin_amdgcn_perm(w1[1], w1[0], 0x05040100u);
    H.u[3] = __builtin_amdgcn_perm(w1[3], w1[2], 0x05040100u);
    L.u[0] = __builtin_amdgcn_perm(w0[1], w0[0], 0x07060302u);
    L.u[1] = __builtin_amdgcn_perm(w0[3], w0[2], 0x07060302u);
    L.u[2] = __builtin_amdgcn_perm(w1[1], w1[0], 0x07060302u);
    L.u[3] = __builtin_amdgcn_perm(w1[3], w1[2], 0x07060302u);
    *ahi = H.v; *alo = L.v;
}

#define MFMA(a, b, c) __builtin_amdgcn_mfma_f32_16x16x32_bf16((a), (b), (c), 0, 0, 0)

// ---------------------------------------------------------------------------
// Persistent GRU — batch-group decomposition. The recurrence is DIAGONAL in
// batch: H_new[m,:] depends only on H[m,:]. 64 blocks = 4 independent groups
// (16 batch rows each) x 16 n-slices. Exchanges are 16-wide and per-group;
// groups never synchronize with each other. XCD = bid&7 = slice&7 -> all
// blocks sharing a weight slice live on one XCD (slice stays L2-hot).
// Per block: 8 waves (H-crew 0-3 on the critical path, X-crew 4-7 computes
// step t+1's X@Wx preacts). H(t-1) lives in one shared 32 KB LDS buffer.
// ---------------------------------------------------------------------------
__global__ void __launch_bounds__(NTHR, 2) gru_seq(
    const float* __restrict__ X, const float* __restrict__ bz,
    const float* __restrict__ br, const float* __restrict__ bh,
    float* __restrict__ out, float* __restrict__ Zt,
    unsigned int* __restrict__ HP, unsigned int* __restrict__ RHP,
    const unsigned short* __restrict__ Bzr, const unsigned short* __restrict__ Bh,
    unsigned int* flags) {
    const int bid  = blockIdx.x;
    const int s    = bid & 15;          // n-slice (XCD = s&7)
    const int g    = bid >> 4;          // batch group
    const int tid  = threadIdx.x;
    const int wv   = tid >> 6;          // 0..7
    const int w4   = wv & 3;            // role-local wave id
    const bool xc  = wv >= 4;
    const int lane = tid & 63;
    const int fm   = lane & 15;
    const int fkc  = lane >> 4;
    const int fk   = fkc * 8;

    __shared__ unsigned int hbufH[16 * 512];      // 32 KB H(t-1) packed
    __shared__ unsigned int hbufR[16 * 512];      // 32 KB RH packed
    __shared__ float xp1[2][4][16][16];           // 8 KB  P1 X-preacts (dbuf)
    __shared__ float xp2a[2][2][16][16];          // 4 KB  P2 X-preacts jh=0
    __shared__ float xp2b[2][2][16][16];          // 4 KB  P2 X-preacts jh=1
    __shared__ float comb[2][256];                // 2 KB  P2 K-combine

    // P1 geometry: slice s owns zr-cols [64s, 64s+64); wave role w4 -> 16 cols
    const int c1 = s * 64 + w4 * 16 + fm;         // zr col 0..1023
    const unsigned short* Bp1 = Bzr + (size_t)c1 * KEFF;
    const bool isz = (c1 < 512);
    const float bias1 = isz ? bz[c1] : br[c1 - 512];

    // P2 geometry: slice s owns h-cols [32s, 32s+32); 2 tiles x 2 K-halves
    const int ti = w4 >> 1, jh = w4 & 1;
    const int c2 = s * 32 + ti * 16 + fm;
    const unsigned short* Bp2 = Bh + (size_t)c2 * KEFF;
    const float bias2 = bh[c2];

    const int key = (fm & 7) << 4;                // ds_read swizzle
    const int sw0 = (32 * fkc) ^ key;
    const int sw1 = (32 * fkc + 16) ^ key;

    unsigned int* HPg  = HP  + g * 8192;          // [16][512] u32, swizzled
    unsigned int* RHPg = RHP + g * 8192;
    float*        Ztg  = Zt  + g * 8192;          // [512][16] f32
    unsigned int* flg  = flags + g * 32;          // 16 flags, 128B-padded group
    const int fidx = (lane < 16) ? lane : 15;

    const float* Xg = X + (size_t)(16 * g + fm) * (T_ * KIN);  // A-row per lane

    // X-crew producers (step t+1, off the critical path) --------------------
    auto xg1 = [&](int tt, int buf) {
        f32x4 acc = {0.f, 0.f, 0.f, 0.f};
        const float* xr = Xg + (size_t)tt * KIN;
#pragma unroll 4
        for (int j = 0; j < 16; ++j) {
            int kp = j * 32 + fk;
            short8 xhi, xlo; cvt_x8(xr, kp, &xhi, &xlo);
            short8 b3 = *(const short8*)(Bp1 + 1536 + kp);
            short8 b4 = *(const short8*)(Bp1 + 2048 + kp);
            short8 b5 = *(const short8*)(Bp1 + 2560 + kp);
            acc = MFMA(xhi, b3, acc); acc = MFMA(xlo, b4, acc); acc = MFMA(xhi, b5, acc);
        }
#pragma unroll
        for (int jj = 0; jj < 4; ++jj) xp1[buf][w4][fkc * 4 + jj][fm] = acc[jj];
    };
    auto xg2 = [&](int tt, int buf) {
        f32x4 acc = {0.f, 0.f, 0.f, 0.f};
        const float* xr = Xg + (size_t)tt * KIN;
#pragma unroll
        for (int j = jh * 8; j < jh * 8 + 8; ++j) {
            int kp = j * 32 + fk;
            short8 xhi, xlo; cvt_x8(xr, kp, &xhi, &xlo);
            short8 b3 = *(const short8*)(Bp2 + 1536 + kp);
            short8 b4 = *(const short8*)(Bp2 + 2048 + kp);
            short8 b5 = *(const short8*)(Bp2 + 2560 + kp);
            acc = MFMA(xhi, b3, acc); acc = MFMA(xlo, b4, acc); acc = MFMA(xhi, b5, acc);
        }
        float (*dst)[16][16] = jh ? xp2b[buf] : xp2a[buf];
#pragma unroll
        for (int jj = 0; jj < 4; ++jj) dst[ti][fkc * 4 + jj][fm] = acc[jj];
    };

    if (xc) { xg1(0, 0); xg2(0, 0); }             // prologue t=0
    __syncthreads();                              // S0

    for (int t = 0; t < T_; ++t) {
        const int bufc = t & 1, bufn = bufc ^ 1;
        const unsigned int ep = (unsigned int)t * 2u;
        // ------------------------- phase 1: Z and R -------------------------
        if (wv == 0 && t) flag_wait16(flg, ep, fidx);  // group's H(t-1) done
        __syncthreads();                               // S1
        if (!xc) {
            // cooperative stage of group H: wave w4 -> rounds 8w4..8w4+8
            const char* srcb = (const char*)HPg;
            char* dstb = (char*)hbufH;
#pragma unroll
            for (int i = 0; i < 8; ++i) {
                int r = w4 * 8 + i;
                __builtin_amdgcn_global_load_lds(
                    (const unsigned int*)(srcb + r * 1024 + lane * 16),
                    (unsigned int*)(dstb + r * 1024), 16, 0, 0x11);
            }
            asm volatile("s_waitcnt vmcnt(0)" ::: "memory");
            __builtin_amdgcn_sched_barrier(0);
        }
        __syncthreads();                               // S1c: H visible to all
        if (!xc) {
            f32x4 acc = {0.f, 0.f, 0.f, 0.f};
            const char* sl = (const char*)hbufH + fm * 2048;
#pragma unroll 4
            for (int j = 0; j < 16; ++j) {
                u32x4 w0 = *(const u32x4*)(sl + 128 * j + sw0);
                u32x4 w1 = *(const u32x4*)(sl + 128 * j + sw1);
                short8 ahi, alo; unpackw(w0, w1, &ahi, &alo);
                int kp = j * 32 + fk;
                short8 b0 = *(const short8*)(Bp1 + kp);
                short8 b1 = *(const short8*)(Bp1 + 512 + kp);
                short8 b2 = *(const short8*)(Bp1 + 1024 + kp);
                acc = MFMA(ahi, b0, acc); acc = MFMA(alo, b1, acc); acc = MFMA(ahi, b2, acc);
            }
            if (isz) {                  // z-gate -> Zt [c][m], 2x ast64
                float gz[4];
#pragma unroll
                for (int jj = 0; jj < 4; ++jj)
                    gz[jj] = 1.f / (1.f + __expf(-(acc[jj] +
                               xp1[bufc][w4][fkc * 4 + jj][fm] + bias1)));
                union { float f[2]; unsigned long long q; } p0, p1;
                p0.f[0] = gz[0]; p0.f[1] = gz[1];
                p1.f[0] = gz[2]; p1.f[1] = gz[3];
                float* zp = Ztg + c1 * 16 + fkc * 4;
                ast64(zp, p0.q); ast64(zp + 2, p1.q);
            } else {                    // r-gate -> RH packed (H from LDS)
                int cr = c1 - 512;
#pragma unroll
                for (int jj = 0; jj < 4; ++jj) {
                    int mr = fkc * 4 + jj;
                    unsigned int hw = *(const unsigned int*)((const char*)hbufH +
                        mr * 2048 + ((4 * cr) ^ ((mr & 7) << 4)));
                    float h  = b2f((unsigned short)(hw & 0xffffu)) +
                               b2f((unsigned short)(hw >> 16));
                    float gr = 1.f / (1.f + __expf(-(acc[jj] +
                                 xp1[bufc][w4][mr][fm] + bias1)));
                    float rh = gr * h;
                    unsigned short hi = f2b(rh);
                    unsigned short lo = f2b(rh - b2f(hi));
                    ast32(RHPg + hp_idx(mr, cr),
                          (unsigned int)hi | ((unsigned int)lo << 16));
                }
            }
        } else if (t + 1 < T_) {
            xg1(t + 1, bufn);           // off-path: next step's P1 X-preacts
        }
        __syncthreads();                               // S2: drains ast stores
        if (tid == 0) ast32(flg + s, ep + 1u);         // B1 arrive (own slot)
        // ------------------------- phase 2: h~ and H update ------------------
        if (wv == 0) flag_wait16(flg, ep + 1u, fidx);  // group's P1 done
        else if (xc && t + 1 < T_) xg2(t + 1, bufn);   // overlaps the poll
        __syncthreads();                               // S3
        unsigned long long zq0 = 0, zq1 = 0;
        if (!xc) {
            if (jh == 0) {              // prefetch Z (hides MALL latency)
                const float* zp = Ztg + c2 * 16 + fkc * 4;
                zq0 = ald64(zp); zq1 = ald64(zp + 2);
            }
            // cooperative stage of group RH
            const char* srcb = (const char*)RHPg;
            char* dstb = (char*)hbufR;
#pragma unroll
            for (int i = 0; i < 8; ++i) {
                int r = w4 * 8 + i;
                __builtin_amdgcn_global_load_lds(
                    (const unsigned int*)(srcb + r * 1024 + lane * 16),
                    (unsigned int*)(dstb + r * 1024), 16, 0, 0x11);
            }
            asm volatile("s_waitcnt vmcnt(0)" ::: "memory");
            __builtin_amdgcn_sched_barrier(0);
        }
        __syncthreads();                               // S3b: RH visible
        f32x4 acc2 = {0.f, 0.f, 0.f, 0.f};
        if (!xc) {
            const char* sl2 = (const char*)hbufR + fm * 2048;
#pragma unroll
            for (int j = jh * 8; j < jh * 8 + 8; ++j) {
                u32x4 w0 = *(const u32x4*)(sl2 + 128 * j + sw0);
                u32x4 w1 = *(const u32x4*)(sl2 + 128 * j + sw1);
                short8 ahi, alo; unpackw(w0, w1, &ahi, &alo);
                int kp = j * 32 + fk;
                short8 b0 = *(const short8*)(Bp2 + kp);
                short8 b1 = *(const short8*)(Bp2 + 512 + kp);
                short8 b2 = *(const short8*)(Bp2 + 1024 + kp);
                acc2 = MFMA(ahi, b0, acc2); acc2 = MFMA(alo, b1, acc2); acc2 = MFMA(ahi, b2, acc2);
            }
            if (jh == 1) {
#pragma unroll
                for (int jj = 0; jj < 4; ++jj)
                    comb[ti][(fkc * 4 + jj) * 16 + fm] = acc2[jj];
            }
        }
        __syncthreads();                               // S4a: comb ready
        if (!xc && jh == 0) {
            union { unsigned long long q; float f[2]; } z0, z1;
            z0.q = zq0; z1.q = zq1;
            float zv[4] = {z0.f[0], z0.f[1], z1.f[0], z1.f[1]};
#pragma unroll
            for (int jj = 0; jj < 4; ++jj) {
                int mr = fkc * 4 + jj;
                unsigned int hw = *(const unsigned int*)((const char*)hbufH +
                    mr * 2048 + ((4 * c2) ^ ((mr & 7) << 4)));
                float h   = b2f((unsigned short)(hw & 0xffffu)) +
                            b2f((unsigned short)(hw >> 16));
                float pre = acc2[jj] + comb[ti][mr * 16 + fm] +
                            xp2a[bufc][ti][mr][fm] + xp2b[bufc][ti][mr][fm] + bias2;
                float e   = __expf(-2.f * pre);
                float ht  = 2.f / (1.f + e) - 1.f;     // tanh
                float hn  = zv[jj] * h + (1.f - zv[jj]) * ht;
                int mg = 16 * g + mr;
                out[(size_t)mg * (T_ * NH) + (size_t)t * NH + c2] = hn;
                if (t == T_ - 1)
                    out[(size_t)B_ * T_ * NH + mg * NH + c2] = hn;
                unsigned short hi = f2b(hn);
                unsigned short lo = f2b(hn - b2f(hi));
                ast32(HPg + hp_idx(mr, c2),
                      (unsigned int)hi | ((unsigned int)lo << 16));
            }
        }
        __syncthreads();                               // S4: drains stores
        if (tid == 0) ast32(flg + s, ep + 2u);         // B2 arrive
    }
}

extern "C" void kernel_launch(void* const* d_in, const int* in_sizes, int n_in,
                              void* d_out, int out_size, void* d_ws, size_t ws_size,
                              hipStream_t stream) {
    (void)in_sizes; (void)n_in; (void)out_size; (void)ws_size;
    const float* X   = (const float*)d_in[0];
    const float* Wxz = (const float*)d_in[1];
    const float* Whz = (const float*)d_in[2];
    const float* bz  = (const float*)d_in[3];
    const float* Wxr = (const float*)d_in[4];
    const float* Whr = (const float*)d_in[5];
    const float* br  = (const float*)d_in[6];
    const float* Wxh = (const float*)d_in[7];
    const float* Whh = (const float*)d_in[8];
    const float* bh  = (const float*)d_in[9];
    float* out = (float*)d_out;

    char* ws = (char*)d_ws;
    unsigned int* flags = (unsigned int*)ws;                   // 4 groups x 128 B
    float* Zt         = (float*)(ws + 8192);                   // 4 x 32 KB [c][m]
    unsigned int* HP  = (unsigned int*)(ws + 8192 + 131072);   // 4 x 32 KB packed+swz
    unsigned int* RHP = (unsigned int*)(ws + 8192 + 262144);   // 4 x 32 KB packed+swz
    unsigned short* Bzr = (unsigned short*)(ws + (1 << 20));   // 6.3 MB
    unsigned short* Bh  = Bzr + (size_t)1024 * KEFF;           // 3.2 MB

    // zero flags + H0 state each call (graph-replay safe)
    hipMemsetAsync(d_ws, 0, 1 << 20, stream);
    prepack<<<dim3(12, 1536), 256, 0, stream>>>(Wxz, Whz, Wxr, Whr, Wxh, Whh, Bzr, Bh);
    gru_seq<<<NBLK, NTHR, 0, stream>>>(X, bz, br, bh, out, Zt, HP, RHP, Bzr, Bh, flags);
}